// Round 1
// baseline (566.997 us; speedup 1.0000x reference)
//
#include <hip/hip_runtime.h>

typedef __attribute__((ext_vector_type(8))) short short8;
typedef __attribute__((ext_vector_type(4))) float floatx4;
typedef __attribute__((ext_vector_type(4))) unsigned short ushort4v;
typedef unsigned short u16;

#define DEV __device__ __forceinline__

DEV u16 f2bf(float f) {
  unsigned int u = __float_as_uint(f);
  u += 0x7fffu + ((u >> 16) & 1u);
  return (u16)(u >> 16);
}
DEV float bf2f(u16 h) { return __uint_as_float(((unsigned int)h) << 16); }
DEV float silu_f(float x) { return x / (1.f + __expf(-x)); }
DEV floatx4 fzero() { floatx4 z = {0.f, 0.f, 0.f, 0.f}; return z; }
DEV floatx4 mfma16(short8 a, short8 b, floatx4 c) {
  return __builtin_amdgcn_mfma_f32_16x16x32_bf16(a, b, c, 0, 0, 0);
}
DEV void gll16(const void* g, void* l) {
  __builtin_amdgcn_global_load_lds((__attribute__((address_space(1))) void*)g,
                                   (__attribute__((address_space(3))) void*)l,
                                   16, 0, 0);
}

// ---------------- cast x (f32 -> bf16) ----------------
__global__ __launch_bounds__(256) void cast_x_kernel(const float* __restrict__ x,
                                                     u16* __restrict__ xb, int n4) {
  int i = blockIdx.x * 256 + threadIdx.x;
  if (i >= n4) return;
  float4 v = ((const float4*)x)[i];
  ushort4v o;
  o[0] = f2bf(v.x); o[1] = f2bf(v.y); o[2] = f2bf(v.z); o[3] = f2bf(v.w);
  *(ushort4v*)&xb[(size_t)i * 4] = o;
}

// ---------------- transpose+cast: W[K][N] f32 -> WT[N][K] bf16 ----------------
__global__ __launch_bounds__(256) void transpose_cast_kernel(const float* __restrict__ W,
                                                             u16* __restrict__ WT,
                                                             int K, int N) {
  __shared__ u16 tile[32][36];
  int n0 = blockIdx.x * 32, k0 = blockIdx.y * 32;
  int t = threadIdx.x;
  int r = t >> 3, cs = (t & 7) * 4;
  float4 v = *(const float4*)&W[(size_t)(k0 + r) * N + n0 + cs];
  tile[r][cs + 0] = f2bf(v.x);
  tile[r][cs + 1] = f2bf(v.y);
  tile[r][cs + 2] = f2bf(v.z);
  tile[r][cs + 3] = f2bf(v.w);
  __syncthreads();
  ushort4v o;
  o[0] = tile[cs + 0][r];
  o[1] = tile[cs + 1][r];
  o[2] = tile[cs + 2][r];
  o[3] = tile[cs + 3][r];
  *(ushort4v*)&WT[(size_t)(n0 + r) * K + k0 + cs] = o;
}

// ---------------- transposed bf16 store helper (wave 64x64 tile in tr[64][72]) ----
DEV void wave_transposed_store(u16* __restrict__ Ct, long chunk_stride,
                               const u16* trw, int chunk, int cbase, int nbase,
                               int lane) {
#pragma unroll
  for (int it = 0; it < 8; ++it) {
    int e_l = it * 8 + (lane >> 3);
    int c_off = (lane & 7) * 8;
    short8 val = *(const short8*)&trw[e_l * 72 + c_off];
    *(short8*)&Ct[(size_t)chunk * chunk_stride + (size_t)(nbase + e_l) * 256 + cbase +
                  c_off] = val;
  }
}

// =====================================================================
// 256x256-tile, BK=64, 8-wave deep-pipelined GEMM (8-phase, counted vmcnt)
// MODE 0: A=xb[16384][1024], Bt=[wvT;wgT][4096][1024].
//         n0<2048 -> v: silu+bias -> transposed chunk store to vT
//         n0>=2048 -> gate: silu+bias -> natural store
// MODE 1: A=gate[16384][2048], Bt=woT[1024][2048] -> fp32 + bias (final out)
//
// LDS: ring of 8 part-slots x 16KB. part h: tile h>>2, A/B = !(h&1),
// k-half = (h>>1)&1. Stage part h at phase h-7 (2 x gll16/thread).
// Part h's last ds_read is phase h; overwrite (part h+8) issues at phase h+1,
// after the post-MFMA barrier of phase h -> race-free.
// Phase q's vmcnt guarantees parts <= q+2 landed for ALL waves once the
// post-phase-q barrier passes -> phase q+1's reads (parts q+1,q+2) are safe.
// =====================================================================

#define PH(SA, SB, NIA, NIB, VML, RDA, STG, HH)                                \
  {                                                                            \
    asm volatile("s_waitcnt vmcnt(" #VML ")" ::: "memory");                    \
    if (RDA) {                                                                 \
      _Pragma("unroll") for (int mi_ = 0; mi_ < 8; ++mi_)                      \
          af[mi_] = *(const short8*)&lds[((SA) * 1024 + aoff + mi_ * 64) * 8]; \
    }                                                                          \
    bf0 = *(const short8*)&lds[((SB) * 1024 + boff + (NIA) * 64) * 8];         \
    bf1 = *(const short8*)&lds[((SB) * 1024 + boff + (NIB) * 64) * 8];         \
    if (STG) STAGE(HH);                                                        \
    asm volatile("" ::: "memory");                                             \
    __builtin_amdgcn_s_barrier();                                              \
    asm volatile("" ::: "memory");                                             \
    __builtin_amdgcn_s_setprio(1);                                             \
    _Pragma("unroll") for (int mi_ = 0; mi_ < 8; ++mi_) {                      \
      acc[mi_][NIA] = mfma16(af[mi_], bf0, acc[mi_][NIA]);                     \
      acc[mi_][NIB] = mfma16(af[mi_], bf1, acc[mi_][NIB]);                     \
    }                                                                          \
    __builtin_amdgcn_s_setprio(0);                                             \
    asm volatile("" ::: "memory");                                             \
    __builtin_amdgcn_s_barrier();                                              \
    asm volatile("" ::: "memory");                                             \
  }

template <int MODE>
__global__ __launch_bounds__(512, 2) void gemm8(
    const u16* __restrict__ A, const u16* __restrict__ Bt,
    const float* __restrict__ bias0, const float* __restrict__ bias1,
    u16* __restrict__ vT, u16* __restrict__ gate, float* __restrict__ Cf) {
  constexpr int KK = (MODE == 0) ? 1024 : 2048;
  constexpr int NN = (MODE == 0) ? 4096 : 1024;
  constexpr int NT = KK / 64;          // K-tiles
  constexpr int NSH = (MODE == 0) ? 4 : 2;  // log2(n-tiles)

  __shared__ u16 lds[8 * 8192];  // 128 KiB: 8 part-slots of 16 KiB

  const int t = threadIdx.x;
  const int wave = t >> 6, lane = t & 63;
  const int l15 = lane & 15, l16 = lane >> 4;
  const int b = blockIdx.x;
  const int xcd = b & 7, i = b >> 3;
  const int m0 = (xcd * 8 + (i >> NSH)) * 256;
  const int n0 = (i & ((1 << NSH) - 1)) * 256;
  const int wm = wave >> 2, wn = wave & 3;  // 2 x 4 wave grid; per-wave 128x64

  // ---- staging geometry: LDS offset16 o holds global (row o>>2, chunk (o&3)^((r>>1)&3))
  const int o0 = wave * 128 + lane;
  const int r0 = o0 >> 2;
  const int p0 = (o0 & 3) ^ ((r0 >> 1) & 3);
  const u16* srcA = A + (size_t)(m0 + r0) * KK + p0 * 8;
  const u16* srcB = Bt + (size_t)(n0 + r0) * KK + p0 * 8;

  auto STAGE = [&](int h) {
    const int slot = h & 7;
    const int koff = (h >> 2) * 64 + ((h >> 1) & 1) * 32;
    u16* dst = &lds[slot * 8192 + o0 * 8];
    const u16* s = ((h & 1) ? srcB : srcA) + koff;
    gll16(s, dst);
    gll16(s + 16 * KK, dst + 512);
  };

  // ---- ds_read swizzled offsets (r>>1 term constant across mi/ni steps of 16)
  const int rA = wm * 128 + l15;
  const int aoff = rA * 4 + (l16 ^ ((rA >> 1) & 3));
  const int rB = wn * 64 + l15;
  const int boff = rB * 4 + (l16 ^ ((rB >> 1) & 3));

  floatx4 acc[8][4];
#pragma unroll
  for (int a = 0; a < 8; ++a)
#pragma unroll
    for (int c = 0; c < 4; ++c) acc[a][c] = fzero();
  short8 af[8], bf0, bf1;

  // ---- prologue: stage parts 0..6, ensure parts 0,1 landed for all waves
#pragma unroll
  for (int h = 0; h < 7; ++h) STAGE(h);
  asm volatile("s_waitcnt vmcnt(10)" ::: "memory");
  asm volatile("" ::: "memory");
  __builtin_amdgcn_s_barrier();
  asm volatile("" ::: "memory");

  // ---- main loop: phases q = 4T+j; steady-state vmcnt(8)
  for (int T = 0; T < NT - 2; ++T) {
    const int s0 = (T & 1) * 4;
    PH(s0, s0 + 1, 0, 1, 8, 1, 1, 4 * T + 7)
    PH(s0, s0 + 1, 2, 3, 8, 0, 1, 4 * T + 8)
    PH(s0 + 2, s0 + 3, 0, 1, 8, 1, 1, 4 * T + 9)
    PH(s0 + 2, s0 + 3, 2, 3, 8, 0, 1, 4 * T + 10)
  }
  {  // T = NT-2: last part (4NT-1) staged in first phase; drain 8,8,6,4
    const int s0 = ((NT - 2) & 1) * 4;
    PH(s0, s0 + 1, 0, 1, 8, 1, 1, 4 * (NT - 2) + 7)
    PH(s0, s0 + 1, 2, 3, 8, 0, 0, 0)
    PH(s0 + 2, s0 + 3, 0, 1, 6, 1, 0, 0)
    PH(s0 + 2, s0 + 3, 2, 3, 4, 0, 0, 0)
  }
  {  // T = NT-1: drain 2,0,0,0
    const int s0 = ((NT - 1) & 1) * 4;
    PH(s0, s0 + 1, 0, 1, 2, 1, 0, 0)
    PH(s0, s0 + 1, 2, 3, 0, 0, 0, 0)
    PH(s0 + 2, s0 + 3, 0, 1, 0, 1, 0, 0)
    PH(s0 + 2, s0 + 3, 2, 3, 0, 0, 0, 0)
  }
  // final post-MFMA barrier has passed: all staging reads done, all loads landed
  // -> LDS reusable as per-wave transpose scratch (8 x 64x72 u16 = 72 KiB)

  if constexpr (MODE == 0) {
    const int chunk = m0 >> 8;
    u16* trw = &lds[wave * (64 * 72)];
    if (n0 < 2048) {
      // ---- v path: silu -> transposed per-chunk store vT[chunk][e][c]
      const int e0 = n0 + wn * 64;
#pragma unroll
      for (int th = 0; th < 2; ++th) {
#pragma unroll
        for (int mi2 = 0; mi2 < 4; ++mi2) {
          const int mi = th * 4 + mi2;
#pragma unroll
          for (int ni = 0; ni < 4; ++ni) {
            const float bc = bias0[e0 + ni * 16 + l15];
            ushort4v pk;
#pragma unroll
            for (int r = 0; r < 4; ++r) pk[r] = f2bf(silu_f(acc[mi][ni][r] + bc));
            *(ushort4v*)&trw[(ni * 16 + l15) * 72 + mi2 * 16 + l16 * 4] = pk;
          }
        }
        wave_transposed_store(vT, 2048L * 256, trw, chunk, wm * 128 + th * 64, e0,
                              lane);
      }
    } else {
      // ---- gate path: silu -> natural coalesced store via LDS transpose
      const int c0 = n0 - 2048 + wn * 64;
#pragma unroll
      for (int th = 0; th < 2; ++th) {
#pragma unroll
        for (int mi2 = 0; mi2 < 4; ++mi2) {
          const int mi = th * 4 + mi2;
#pragma unroll
          for (int ni = 0; ni < 4; ++ni) {
            const float bc = bias1[c0 + ni * 16 + l15];
#pragma unroll
            for (int r = 0; r < 4; ++r)
              trw[(mi2 * 16 + l16 * 4 + r) * 72 + ni * 16 + l15] =
                  f2bf(silu_f(acc[mi][ni][r] + bc));
          }
        }
#pragma unroll
        for (int it = 0; it < 8; ++it) {
          const int m_l = it * 8 + (lane >> 3);
          const int n_off = (lane & 7) * 8;
          *(short8*)&gate[(size_t)(m0 + wm * 128 + th * 64 + m_l) * 2048 + c0 +
                          n_off] = *(const short8*)&trw[m_l * 72 + n_off];
        }
      }
    }
  } else {
    // ---- final output: fp32 + bias, natural
#pragma unroll
    for (int mi = 0; mi < 8; ++mi)
#pragma unroll
      for (int ni = 0; ni < 4; ++ni) {
        const int col = n0 + wn * 64 + ni * 16 + l15;
        const float bc = bias0[col];
        const int row = m0 + wm * 128 + mi * 16 + l16 * 4;
#pragma unroll
        for (int r = 0; r < 4; ++r)
          Cf[(size_t)(row + r) * NN + col] = acc[mi][ni][r] + bc;
      }
  }
}

// ---------------- GEMM: C = A[M,K] * Bt[N,K]^T, bf16 MFMA, 128x128, BK=64 ------
// MODE 2: silu -> qq/qk/lq natural (affine) + lkT transposed (affine)
template <int MODE>
__global__ __launch_bounds__(256) void gemm_bt(
    const u16* __restrict__ A, const u16* __restrict__ Bt, int M, int N, int K,
    int nshift, const float* __restrict__ bias, u16* __restrict__ Cn,
    float* __restrict__ Cf, u16* __restrict__ Ct, long ct_stride,
    u16* __restrict__ Cn2, u16* __restrict__ Cn3,
    const float* __restrict__ gqq, const float* __restrict__ bqq,
    const float* __restrict__ gqk, const float* __restrict__ bqk,
    const float* __restrict__ glq, const float* __restrict__ blq,
    const float* __restrict__ glk, const float* __restrict__ blk) {
  __shared__ union {
    struct { u16 a[128 * 64]; u16 b[128 * 64]; } st;
    u16 tr[4 * 64 * 72];
  } sm;
  const int t = threadIdx.x;
  const int wave = t >> 6, lane = t & 63;
  const int l15 = lane & 15, l16 = lane >> 4;
  const int ell = blockIdx.x;
  const int xcd = ell & 7, i = ell >> 3;
  const int mtiles_per_xcd = M >> 10;
  const int m0 = (xcd * mtiles_per_xcd + (i >> nshift)) * 128;
  const int n0 = (i & ((1 << nshift) - 1)) * 128;
  const int wm = (wave >> 1) * 64, wn = (wave & 1) * 64;

  floatx4 acc[4][4];
#pragma unroll
  for (int i2 = 0; i2 < 4; ++i2)
#pragma unroll
    for (int j = 0; j < 4; ++j) acc[i2][j] = fzero();

  const u16* pa[4];
  const u16* pb[4];
#pragma unroll
  for (int j = 0; j < 4; ++j) {
    const int c = t + 256 * j;
    const int r = c >> 3, p = c & 7;
    const int g = p ^ (r & 7);
    pa[j] = A + (size_t)(m0 + r) * K + g * 8;
    pb[j] = Bt + (size_t)(n0 + r) * K + g * 8;
  }

  for (int k0 = 0; k0 < K; k0 += 64) {
    __syncthreads();
#pragma unroll
    for (int j = 0; j < 4; ++j) {
      gll16(pa[j] + k0, &sm.st.a[(t + 256 * j) * 8]);
      gll16(pb[j] + k0, &sm.st.b[(t + 256 * j) * 8]);
    }
    __syncthreads();
#pragma unroll
    for (int s = 0; s < 2; ++s) {
      short8 af[4], bfr[4];
#pragma unroll
      for (int mi = 0; mi < 4; ++mi) {
        const int wr = wm + mi * 16 + l15;
        af[mi] = *(const short8*)&sm.st.a[wr * 64 + ((s * 4 + l16) ^ (wr & 7)) * 8];
      }
#pragma unroll
      for (int ni = 0; ni < 4; ++ni) {
        const int wr = wn + ni * 16 + l15;
        bfr[ni] = *(const short8*)&sm.st.b[wr * 64 + ((s * 4 + l16) ^ (wr & 7)) * 8];
      }
#pragma unroll
      for (int mi = 0; mi < 4; ++mi)
#pragma unroll
        for (int ni = 0; ni < 4; ++ni)
          acc[mi][ni] = mfma16(af[mi], bfr[ni], acc[mi][ni]);
    }
  }
  __syncthreads();

  if constexpr (MODE == 3) {
#pragma unroll
    for (int mi = 0; mi < 4; ++mi)
#pragma unroll
      for (int ni = 0; ni < 4; ++ni) {
        const int col = n0 + wn + ni * 16 + l15;
        const float bc = bias[col];
        const int row = m0 + wm + mi * 16 + l16 * 4;
#pragma unroll
        for (int r = 0; r < 4; ++r)
          Cf[(size_t)(row + r) * N + col] = acc[mi][ni][r] + bc;
      }
  } else {  // MODE 2
    u16* trw = &sm.tr[wave * 64 * 72];
#pragma unroll
    for (int mi = 0; mi < 4; ++mi)
#pragma unroll
      for (int ni = 0; ni < 4; ++ni) {
        const int col = wn + ni * 16 + l15;
        const float bc = bias[col];
        const float Gqq = gqq[col], Bqq = bqq[col];
        const float Gqk = gqk[col], Bqk = bqk[col];
        const float Glq = glq[col], Blq = blq[col];
        const float Glk = glk[col], Blk = blk[col];
        const int row = m0 + wm + mi * 16 + l16 * 4;
        ushort4v p;
#pragma unroll
        for (int r = 0; r < 4; ++r) {
          const float sv = silu_f(acc[mi][ni][r] + bc);
          const size_t ad = (size_t)(row + r) * N + col;
          Cn[ad] = f2bf(sv * Gqq + Bqq);
          Cn2[ad] = f2bf(sv * Gqk + Bqk);
          Cn3[ad] = f2bf(sv * Glq + Blq);
          p[r] = f2bf(sv * Glk + Blk);
        }
        *(ushort4v*)&trw[(ni * 16 + l15) * 72 + mi * 16 + l16 * 4] = p;
      }
    wave_transposed_store(Ct, ct_stride, trw, (m0 + wm) >> 8, (m0 + wm) & 255, wn,
                          lane);
  }
}

// ---------------- per-chunk kv[e][h] = sum_c vT[e][c]*lkT[h][c] ----------------
__global__ __launch_bounds__(256) void kv_kernel(const u16* __restrict__ vT,
                                                 const u16* __restrict__ lkT,
                                                 u16* __restrict__ kv) {
  const int chunk = blockIdx.y;
  const int et = blockIdx.x;  // e-block of 128
  const int w = threadIdx.x >> 6, lane = threadIdx.x & 63;
  const int l15 = lane & 15, l16 = lane >> 4;
  const size_t vb = (size_t)chunk * (2048 * 256) + (size_t)et * (128 * 256);
  const size_t lb = (size_t)chunk * (128 * 256);
  const int we = (w >> 1) * 64, wh = (w & 1) * 64;
  floatx4 acc[4][4];
#pragma unroll
  for (int i = 0; i < 4; ++i)
#pragma unroll
    for (int j = 0; j < 4; ++j) acc[i][j] = fzero();
  for (int kk = 0; kk < 8; ++kk) {
    short8 av[4], bv[4];
#pragma unroll
    for (int mi = 0; mi < 4; ++mi)
      av[mi] = *(const short8*)&vT[vb + (size_t)(we + mi * 16 + l15) * 256 + kk * 32 +
                                   l16 * 8];
#pragma unroll
    for (int ni = 0; ni < 4; ++ni)
      bv[ni] = *(const short8*)&lkT[lb + (size_t)(wh + ni * 16 + l15) * 256 + kk * 32 +
                                    l16 * 8];
#pragma unroll
    for (int mi = 0; mi < 4; ++mi)
#pragma unroll
      for (int ni = 0; ni < 4; ++ni) acc[mi][ni] = mfma16(av[mi], bv[ni], acc[mi][ni]);
  }
  u16* out = kv + (size_t)chunk * (2048 * 128);
#pragma unroll
  for (int mi = 0; mi < 4; ++mi)
#pragma unroll
    for (int ni = 0; ni < 4; ++ni) {
      const int h = wh + ni * 16 + l15;
      const int e = et * 128 + we + mi * 16 + l16 * 4;
#pragma unroll
      for (int r = 0; r < 4; ++r) out[(size_t)(e + r) * 128 + h] = f2bf(acc[mi][ni][r]);
    }
}

// ---------------- exclusive cumsum over chunks (in place, bf16) ----------------
__global__ __launch_bounds__(256) void cumsum_kernel(u16* __restrict__ kv) {
  const int idx = blockIdx.x * 256 + threadIdx.x;  // 0..262143 (= 2048*128)
  const int b = blockIdx.y;
  float s = 0.f;
  for (int g = 0; g < 16; ++g) {
    const size_t a = (size_t)(b * 16 + g) * 262144 + idx;
    const float v = bf2f(kv[a]);
    kv[a] = f2bf(s);
    s += v;
  }
}

// ---------------- fused chunk attention ----------------
__global__ __launch_bounds__(256) void attn_kernel(
    const u16* __restrict__ qq, const u16* __restrict__ qk, const u16* __restrict__ lq,
    const u16* __restrict__ vT, const u16* __restrict__ kvT,
    u16* __restrict__ gate_op) {
  __shared__ u16 S[64][264];
  const int chunk = blockIdx.y;
  const int e0 = blockIdx.x * 256;
  const int tok0 = chunk * 256;
  const int w = threadIdx.x >> 6, lane = threadIdx.x & 63;
  const int l15 = lane & 15, l16 = lane >> 4;
  const float isc = 0.022097086912079608f;  // 1/sqrt(2048)
  const size_t vbase = (size_t)chunk * (2048 * 256);
  const size_t kbase = (size_t)chunk * (2048 * 128);
  const int ew = e0 + w * 64;

  for (int ns = 0; ns < 4; ++ns) {
    // ---- phase 1: S rows [ns*64+w*16, +16) = relu^2(mask(qq*qk^T/scale))
    const int r0 = ns * 64 + w * 16;
    short8 af[4];
#pragma unroll
    for (int kk = 0; kk < 4; ++kk)
      af[kk] = *(const short8*)&qq[(size_t)(tok0 + r0 + l15) * 128 + kk * 32 + l16 * 8];
    const int mt_cnt = (r0 >> 4) + 1;   // tiles with any unmasked entry
    const int mt_all = (ns + 1) * 4;    // tiles phase 2 will read
    const int srow = w * 16 + l16 * 4;
    for (int mt = 0; mt < mt_all; ++mt) {
      if (mt < mt_cnt) {
        floatx4 a = fzero();
#pragma unroll
        for (int kk = 0; kk < 4; ++kk) {
          short8 bq =
              *(const short8*)&qk[(size_t)(tok0 + mt * 16 + l15) * 128 + kk * 32 +
                                  l16 * 8];
          a = mfma16(af[kk], bq, a);
        }
        const int mcol = mt * 16 + l15;
#pragma unroll
        for (int r = 0; r < 4; ++r) {
          const int nrow = r0 + l16 * 4 + r;
          float sv = a[r] * isc;
          sv = (mcol <= nrow) ? sv : 0.f;
          sv = fmaxf(sv, 0.f);
          S[srow + r][mcol] = f2bf(sv * sv);
        }
      } else {
#pragma unroll
        for (int r = 0; r < 4; ++r) S[srow + r][mt * 16 + l15] = (u16)0;
      }
    }
    __syncthreads();

    // ---- phase 2: (S@v + lin_q@kv) * gate, wave covers e cols [ew, ew+64)
    floatx4 acc[4][4];
#pragma unroll
    for (int i = 0; i < 4; ++i)
#pragma unroll
      for (int j = 0; j < 4; ++j) acc[i][j] = fzero();

    const int ks = (ns + 1) * 2;  // causal truncation of K range
    for (int kk = 0; kk < ks; ++kk) {
      short8 sa[4];
#pragma unroll
      for (int nt = 0; nt < 4; ++nt)
        sa[nt] = *(const short8*)&S[nt * 16 + l15][kk * 32 + l16 * 8];
#pragma unroll
      for (int ei = 0; ei < 4; ++ei) {
        short8 vb = *(const short8*)&vT[vbase + (size_t)(ew + ei * 16 + l15) * 256 +
                                        kk * 32 + l16 * 8];
#pragma unroll
        for (int nt = 0; nt < 4; ++nt) acc[nt][ei] = mfma16(sa[nt], vb, acc[nt][ei]);
      }
    }
#pragma unroll
    for (int kk = 0; kk < 4; ++kk) {
      short8 la[4];
#pragma unroll
      for (int nt = 0; nt < 4; ++nt)
        la[nt] = *(const short8*)&lq[(size_t)(tok0 + ns * 64 + nt * 16 + l15) * 128 +
                                     kk * 32 + l16 * 8];
#pragma unroll
      for (int ei = 0; ei < 4; ++ei) {
        short8 kb = *(const short8*)&kvT[kbase + (size_t)(ew + ei * 16 + l15) * 128 +
                                         kk * 32 + l16 * 8];
#pragma unroll
        for (int nt = 0; nt < 4; ++nt) acc[nt][ei] = mfma16(la[nt], kb, acc[nt][ei]);
      }
    }
#pragma unroll
    for (int nt = 0; nt < 4; ++nt)
#pragma unroll
      for (int ei = 0; ei < 4; ++ei) {
        const int e_g = ew + ei * 16 + l15;
        const int nb = tok0 + ns * 64 + nt * 16 + l16 * 4;
#pragma unroll
        for (int r = 0; r < 4; ++r) {
          const size_t ad = (size_t)(nb + r) * 2048 + e_g;
          const float gv = bf2f(gate_op[ad]);
          gate_op[ad] = f2bf(acc[nt][ei][r] * gv);
        }
      }
    __syncthreads();
  }
}

extern "C" void kernel_launch(void* const* d_in, const int* in_sizes, int n_in,
                              void* d_out, int out_size, void* d_ws, size_t ws_size,
                              hipStream_t stream) {
  (void)in_sizes; (void)n_in; (void)out_size; (void)ws_size;
  const float* x = (const float*)d_in[0];
  const float* Wv = (const float*)d_in[1];
  const float* bv = (const float*)d_in[2];
  const float* Wg = (const float*)d_in[3];
  const float* bg = (const float*)d_in[4];
  const float* Win = (const float*)d_in[5];
  const float* bin = (const float*)d_in[6];
  const float* Wout = (const float*)d_in[7];
  const float* bout = (const float*)d_in[8];
  const float* gqq = (const float*)d_in[9];
  const float* bqq = (const float*)d_in[10];
  const float* gqk = (const float*)d_in[11];
  const float* bqk = (const float*)d_in[12];
  const float* glq = (const float*)d_in[13];
  const float* blq = (const float*)d_in[14];
  const float* glk = (const float*)d_in[15];
  const float* blk = (const float*)d_in[16];

  char* p = (char*)d_ws;
  u16* xb = (u16*)p;   p += (size_t)16384 * 1024 * 2;
  u16* wvT = (u16*)p;  p += (size_t)2048 * 1024 * 2;   // [wvT; wgT] = merged Bt[4096][1024]
  u16* wgT = (u16*)p;  p += (size_t)2048 * 1024 * 2;
  u16* winT = (u16*)p; p += (size_t)128 * 1024 * 2;
  u16* woT = (u16*)p;  p += (size_t)1024 * 2048 * 2;
  u16* vTb = (u16*)p;  p += (size_t)64 * 2048 * 256 * 2;
  u16* gate = (u16*)p; p += (size_t)16384 * 2048 * 2;  // gate, then op (in place)
  u16* qqb = (u16*)p;  p += (size_t)16384 * 128 * 2;
  u16* qkb = (u16*)p;  p += (size_t)16384 * 128 * 2;
  u16* lqb = (u16*)p;  p += (size_t)16384 * 128 * 2;
  u16* lkTb = (u16*)p; p += (size_t)64 * 128 * 256 * 2;
  u16* kvb = (u16*)p;  p += (size_t)64 * 2048 * 128 * 2;

  cast_x_kernel<<<16384, 256, 0, stream>>>(x, xb, 4194304);
  transpose_cast_kernel<<<dim3(64, 32), 256, 0, stream>>>(Wv, wvT, 1024, 2048);
  transpose_cast_kernel<<<dim3(64, 32), 256, 0, stream>>>(Wg, wgT, 1024, 2048);
  transpose_cast_kernel<<<dim3(4, 32), 256, 0, stream>>>(Win, winT, 1024, 128);
  transpose_cast_kernel<<<dim3(32, 64), 256, 0, stream>>>(Wout, woT, 2048, 1024);

  // merged v+gate GEMM: M=16384, N=4096 ([v | gate]), K=1024, 256^2 tiles
  gemm8<0><<<1024, 512, 0, stream>>>(xb, wvT, bv, bg, vTb, gate, nullptr);

  gemm_bt<2><<<128, 256, 0, stream>>>(
      xb, winT, 16384, 128, 1024, 0, bin, qqb, nullptr, lkTb, 128L * 256, qkb, lqb,
      gqq, bqq, gqk, bqk, glq, blq, glk, blk);

  kv_kernel<<<dim3(16, 64), 256, 0, stream>>>(vTb, lkTb, kvb);
  cumsum_kernel<<<dim3(1024, 4), 256, 0, stream>>>(kvb);
  attn_kernel<<<dim3(8, 64), 256, 0, stream>>>(qqb, qkb, lqb, vTb, kvb, gate);

  // final GEMM: M=16384, N=1024, K=2048, 256^2 tiles, fp32 + bias
  gemm8<1><<<256, 512, 0, stream>>>(gate, woT, bout, nullptr, nullptr, nullptr,
                                    (float*)d_out);
}

// Round 2
// 555.146 us; speedup vs baseline: 1.0213x; 1.0213x over previous
//
#include <hip/hip_runtime.h>

typedef __attribute__((ext_vector_type(8))) short short8;
typedef __attribute__((ext_vector_type(4))) float floatx4;
typedef __attribute__((ext_vector_type(4))) unsigned short ushort4v;
typedef unsigned short u16;

#define DEV __device__ __forceinline__

DEV u16 f2bf(float f) {
  unsigned int u = __float_as_uint(f);
  u += 0x7fffu + ((u >> 16) & 1u);
  return (u16)(u >> 16);
}
DEV float bf2f(u16 h) { return __uint_as_float(((unsigned int)h) << 16); }
DEV float silu_f(float x) { return x / (1.f + __expf(-x)); }
DEV floatx4 fzero() { floatx4 z = {0.f, 0.f, 0.f, 0.f}; return z; }
DEV floatx4 mfma16(short8 a, short8 b, floatx4 c) {
  return __builtin_amdgcn_mfma_f32_16x16x32_bf16(a, b, c, 0, 0, 0);
}
DEV void gll16(const void* g, void* l) {
  __builtin_amdgcn_global_load_lds((__attribute__((address_space(1))) void*)g,
                                   (__attribute__((address_space(3))) void*)l,
                                   16, 0, 0);
}

// ---------------- cast x (f32 -> bf16) ----------------
__global__ __launch_bounds__(256) void cast_x_kernel(const float* __restrict__ x,
                                                     u16* __restrict__ xb, int n4) {
  int i = blockIdx.x * 256 + threadIdx.x;
  if (i >= n4) return;
  float4 v = ((const float4*)x)[i];
  ushort4v o;
  o[0] = f2bf(v.x); o[1] = f2bf(v.y); o[2] = f2bf(v.z); o[3] = f2bf(v.w);
  *(ushort4v*)&xb[(size_t)i * 4] = o;
}

// ---------------- transpose+cast: W[K][N] f32 -> WT[N][K] bf16 ----------------
__global__ __launch_bounds__(256) void transpose_cast_kernel(const float* __restrict__ W,
                                                             u16* __restrict__ WT,
                                                             int K, int N) {
  __shared__ u16 tile[32][36];
  int n0 = blockIdx.x * 32, k0 = blockIdx.y * 32;
  int t = threadIdx.x;
  int r = t >> 3, cs = (t & 7) * 4;
  float4 v = *(const float4*)&W[(size_t)(k0 + r) * N + n0 + cs];
  tile[r][cs + 0] = f2bf(v.x);
  tile[r][cs + 1] = f2bf(v.y);
  tile[r][cs + 2] = f2bf(v.z);
  tile[r][cs + 3] = f2bf(v.w);
  __syncthreads();
  ushort4v o;
  o[0] = tile[cs + 0][r];
  o[1] = tile[cs + 1][r];
  o[2] = tile[cs + 2][r];
  o[3] = tile[cs + 3][r];
  *(ushort4v*)&WT[(size_t)(n0 + r) * K + k0 + cs] = o;
}

// ---------------- transposed bf16 store helper (wave 64x64 tile in tr[64][72]) ----
DEV void wave_transposed_store(u16* __restrict__ Ct, long chunk_stride,
                               const u16* trw, int chunk, int cbase, int nbase,
                               int lane) {
#pragma unroll
  for (int it = 0; it < 8; ++it) {
    int e_l = it * 8 + (lane >> 3);
    int c_off = (lane & 7) * 8;
    short8 val = *(const short8*)&trw[e_l * 72 + c_off];
    *(short8*)&Ct[(size_t)chunk * chunk_stride + (size_t)(nbase + e_l) * 256 + cbase +
                  c_off] = val;
  }
}

// =====================================================================
// 256x256-tile, BK=64, 8-wave pipelined GEMM.
// v2 schedule: 2 phases per K-tile, 1 barrier + 1 vmcnt per phase.
// Phase q (tile T=q>>1, k-half q&1):
//   vmcnt(4) -> STAGE parts 2q+6,2q+7 -> ds_read af[8]+bf[4] -> 32 MFMA -> barrier
// Ring: 8 part-slots x 16KB. Part h = (tile h>>2, k-half (h>>1)&1, A/B h&1),
// slot h&7. Part h staged at phase (h-6)/2, last read at phase h/2 (parts read
// at phase q are 2q, 2q+1); previous slot occupant h-8 last read at phase
// q-1 -> one barrier between read and overwrite. Gate math (loads, 2/part):
// at top of phase q issued 4q+12, next phase needs parts <= 2q+3 = 4q+8
// retired -> vmcnt(4); drain 4,4,0,0. Prologue: parts 0..5, vmcnt(8).
// =====================================================================

#define PH2(SA, SB, VML, STG, HH)                                            \
  {                                                                          \
    asm volatile("s_waitcnt vmcnt(" #VML ")" ::: "memory");                  \
    if (STG) { STAGE(HH); STAGE((HH) + 1); }                                 \
    _Pragma("unroll") for (int mi_ = 0; mi_ < 8; ++mi_)                      \
        af[mi_] = *(const short8*)&lds[((SA) * 1024 + aoff + mi_ * 64) * 8]; \
    _Pragma("unroll") for (int ni_ = 0; ni_ < 4; ++ni_)                      \
        bf[ni_] = *(const short8*)&lds[((SB) * 1024 + boff + ni_ * 64) * 8]; \
    asm volatile("" ::: "memory");                                           \
    __builtin_amdgcn_s_setprio(1);                                           \
    _Pragma("unroll") for (int mi_ = 0; mi_ < 8; ++mi_)                      \
      _Pragma("unroll") for (int ni_ = 0; ni_ < 4; ++ni_)                    \
          acc[mi_][ni_] = mfma16(af[mi_], bf[ni_], acc[mi_][ni_]);           \
    __builtin_amdgcn_s_setprio(0);                                           \
    asm volatile("" ::: "memory");                                           \
    __builtin_amdgcn_s_barrier();                                            \
    asm volatile("" ::: "memory");                                           \
  }

template <int MODE>
__global__ __launch_bounds__(512, 2) void gemm8(
    const u16* __restrict__ A, const u16* __restrict__ Bt,
    const float* __restrict__ bias0, const float* __restrict__ bias1,
    u16* __restrict__ vT, u16* __restrict__ gate, float* __restrict__ Cf) {
  constexpr int KK = (MODE == 0) ? 1024 : 2048;
  constexpr int NN = (MODE == 0) ? 4096 : 1024;
  constexpr int NT = KK / 64;               // K-tiles
  constexpr int NSH = (MODE == 0) ? 4 : 2;  // log2(n-tiles)

  __shared__ u16 lds[8 * 8192];  // 128 KiB: 8 part-slots of 16 KiB

  const int t = threadIdx.x;
  const int wave = t >> 6, lane = t & 63;
  const int l15 = lane & 15, l16 = lane >> 4;
  const int b = blockIdx.x;
  const int xcd = b & 7, i = b >> 3;
  const int m0 = (xcd * 8 + (i >> NSH)) * 256;
  const int n0 = (i & ((1 << NSH) - 1)) * 256;
  const int wm = wave >> 2, wn = wave & 3;  // 2 x 4 wave grid; per-wave 128x64

  // ---- staging geometry: LDS offset16 o holds global (row o>>2, chunk (o&3)^((r>>1)&3))
  const int o0 = wave * 128 + lane;
  const int r0 = o0 >> 2;
  const int p0 = (o0 & 3) ^ ((r0 >> 1) & 3);
  const u16* srcA = A + (size_t)(m0 + r0) * KK + p0 * 8;
  const u16* srcB = Bt + (size_t)(n0 + r0) * KK + p0 * 8;

  auto STAGE = [&](int h) {
    const int slot = h & 7;
    const int koff = (h >> 2) * 64 + ((h >> 1) & 1) * 32;
    u16* dst = &lds[slot * 8192 + o0 * 8];
    const u16* s = ((h & 1) ? srcB : srcA) + koff;
    gll16(s, dst);
    gll16(s + 16 * KK, dst + 512);
  };

  // ---- ds_read swizzled offsets (r>>1 term constant across mi/ni steps of 16)
  const int rA = wm * 128 + l15;
  const int aoff = rA * 4 + (l16 ^ ((rA >> 1) & 3));
  const int rB = wn * 64 + l15;
  const int boff = rB * 4 + (l16 ^ ((rB >> 1) & 3));

  floatx4 acc[8][4];
#pragma unroll
  for (int a = 0; a < 8; ++a)
#pragma unroll
    for (int c = 0; c < 4; ++c) acc[a][c] = fzero();
  short8 af[8], bf[4];

  // ---- prologue: stage parts 0..5, ensure parts 0,1 landed for all waves
#pragma unroll
  for (int h = 0; h < 6; ++h) STAGE(h);
  asm volatile("s_waitcnt vmcnt(8)" ::: "memory");
  asm volatile("" ::: "memory");
  __builtin_amdgcn_s_barrier();
  asm volatile("" ::: "memory");

  // ---- main loop: phases q = 2T + j; steady-state vmcnt(4)
  for (int T = 0; T < NT - 2; ++T) {
    const int s0 = (T & 1) * 4;
    PH2(s0, s0 + 1, 4, 1, 4 * T + 6)
    PH2(s0 + 2, s0 + 3, 4, 1, 4 * T + 8)
  }
  {  // T = NT-2: first phase stages last parts (4NT-2, 4NT-1)
    const int s0 = ((NT - 2) & 1) * 4;
    PH2(s0, s0 + 1, 4, 1, 4 * (NT - 2) + 6)
    PH2(s0 + 2, s0 + 3, 4, 0, 0)
  }
  {  // T = NT-1: drain 0,0
    const int s0 = ((NT - 1) & 1) * 4;
    PH2(s0, s0 + 1, 0, 0, 0)
    PH2(s0 + 2, s0 + 3, 0, 0, 0)
  }
  // final barrier passed: all staging reads done, all loads landed
  // -> LDS reusable as per-wave transpose scratch (8 x 64x72 u16 = 72 KiB)

  if constexpr (MODE == 0) {
    const int chunk = m0 >> 8;
    u16* trw = &lds[wave * (64 * 72)];
    if (n0 < 2048) {
      // ---- v path: silu -> transposed per-chunk store vT[chunk][e][c]
      const int e0 = n0 + wn * 64;
#pragma unroll
      for (int th = 0; th < 2; ++th) {
#pragma unroll
        for (int mi2 = 0; mi2 < 4; ++mi2) {
          const int mi = th * 4 + mi2;
#pragma unroll
          for (int ni = 0; ni < 4; ++ni) {
            const float bc = bias0[e0 + ni * 16 + l15];
            ushort4v pk;
#pragma unroll
            for (int r = 0; r < 4; ++r) pk[r] = f2bf(silu_f(acc[mi][ni][r] + bc));
            *(ushort4v*)&trw[(ni * 16 + l15) * 72 + mi2 * 16 + l16 * 4] = pk;
          }
        }
        wave_transposed_store(vT, 2048L * 256, trw, chunk, wm * 128 + th * 64, e0,
                              lane);
      }
    } else {
      // ---- gate path: silu -> natural coalesced store via LDS transpose
      const int c0 = n0 - 2048 + wn * 64;
#pragma unroll
      for (int th = 0; th < 2; ++th) {
#pragma unroll
        for (int mi2 = 0; mi2 < 4; ++mi2) {
          const int mi = th * 4 + mi2;
#pragma unroll
          for (int ni = 0; ni < 4; ++ni) {
            const float bc = bias1[c0 + ni * 16 + l15];
#pragma unroll
            for (int r = 0; r < 4; ++r)
              trw[(mi2 * 16 + l16 * 4 + r) * 72 + ni * 16 + l15] =
                  f2bf(silu_f(acc[mi][ni][r] + bc));
          }
        }
#pragma unroll
        for (int it = 0; it < 8; ++it) {
          const int m_l = it * 8 + (lane >> 3);
          const int n_off = (lane & 7) * 8;
          *(short8*)&gate[(size_t)(m0 + wm * 128 + th * 64 + m_l) * 2048 + c0 +
                          n_off] = *(const short8*)&trw[m_l * 72 + n_off];
        }
      }
    }
  } else {
    // ---- final output: fp32 + bias, natural
#pragma unroll
    for (int mi = 0; mi < 8; ++mi)
#pragma unroll
      for (int ni = 0; ni < 4; ++ni) {
        const int col = n0 + wn * 64 + ni * 16 + l15;
        const float bc = bias0[col];
        const int row = m0 + wm * 128 + mi * 16 + l16 * 4;
#pragma unroll
        for (int r = 0; r < 4; ++r)
          Cf[(size_t)(row + r) * NN + col] = acc[mi][ni][r] + bc;
      }
  }
}

// ---------------- GEMM: C = A[M,K] * Bt[N,K]^T, bf16 MFMA, 128x128, BK=64 ------
// MODE 2: silu -> qq/qk/lq natural (affine) + lkT transposed (affine)
template <int MODE>
__global__ __launch_bounds__(256) void gemm_bt(
    const u16* __restrict__ A, const u16* __restrict__ Bt, int M, int N, int K,
    int nshift, const float* __restrict__ bias, u16* __restrict__ Cn,
    float* __restrict__ Cf, u16* __restrict__ Ct, long ct_stride,
    u16* __restrict__ Cn2, u16* __restrict__ Cn3,
    const float* __restrict__ gqq, const float* __restrict__ bqq,
    const float* __restrict__ gqk, const float* __restrict__ bqk,
    const float* __restrict__ glq, const float* __restrict__ blq,
    const float* __restrict__ glk, const float* __restrict__ blk) {
  __shared__ union {
    struct { u16 a[128 * 64]; u16 b[128 * 64]; } st;
    u16 tr[4 * 64 * 72];
  } sm;
  const int t = threadIdx.x;
  const int wave = t >> 6, lane = t & 63;
  const int l15 = lane & 15, l16 = lane >> 4;
  const int ell = blockIdx.x;
  const int xcd = ell & 7, i = ell >> 3;
  const int mtiles_per_xcd = M >> 10;
  const int m0 = (xcd * mtiles_per_xcd + (i >> nshift)) * 128;
  const int n0 = (i & ((1 << nshift) - 1)) * 128;
  const int wm = (wave >> 1) * 64, wn = (wave & 1) * 64;

  floatx4 acc[4][4];
#pragma unroll
  for (int i2 = 0; i2 < 4; ++i2)
#pragma unroll
    for (int j = 0; j < 4; ++j) acc[i2][j] = fzero();

  const u16* pa[4];
  const u16* pb[4];
#pragma unroll
  for (int j = 0; j < 4; ++j) {
    const int c = t + 256 * j;
    const int r = c >> 3, p = c & 7;
    const int g = p ^ (r & 7);
    pa[j] = A + (size_t)(m0 + r) * K + g * 8;
    pb[j] = Bt + (size_t)(n0 + r) * K + g * 8;
  }

  for (int k0 = 0; k0 < K; k0 += 64) {
    __syncthreads();
#pragma unroll
    for (int j = 0; j < 4; ++j) {
      gll16(pa[j] + k0, &sm.st.a[(t + 256 * j) * 8]);
      gll16(pb[j] + k0, &sm.st.b[(t + 256 * j) * 8]);
    }
    __syncthreads();
#pragma unroll
    for (int s = 0; s < 2; ++s) {
      short8 af[4], bfr[4];
#pragma unroll
      for (int mi = 0; mi < 4; ++mi) {
        const int wr = wm + mi * 16 + l15;
        af[mi] = *(const short8*)&sm.st.a[wr * 64 + ((s * 4 + l16) ^ (wr & 7)) * 8];
      }
#pragma unroll
      for (int ni = 0; ni < 4; ++ni) {
        const int wr = wn + ni * 16 + l15;
        bfr[ni] = *(const short8*)&sm.st.b[wr * 64 + ((s * 4 + l16) ^ (wr & 7)) * 8];
      }
#pragma unroll
      for (int mi = 0; mi < 4; ++mi)
#pragma unroll
        for (int ni = 0; ni < 4; ++ni)
          acc[mi][ni] = mfma16(af[mi], bfr[ni], acc[mi][ni]);
    }
  }
  __syncthreads();

  if constexpr (MODE == 3) {
#pragma unroll
    for (int mi = 0; mi < 4; ++mi)
#pragma unroll
      for (int ni = 0; ni < 4; ++ni) {
        const int col = n0 + wn + ni * 16 + l15;
        const float bc = bias[col];
        const int row = m0 + wm + mi * 16 + l16 * 4;
#pragma unroll
        for (int r = 0; r < 4; ++r)
          Cf[(size_t)(row + r) * N + col] = acc[mi][ni][r] + bc;
      }
  } else {  // MODE 2
    u16* trw = &sm.tr[wave * 64 * 72];
#pragma unroll
    for (int mi = 0; mi < 4; ++mi)
#pragma unroll
      for (int ni = 0; ni < 4; ++ni) {
        const int col = wn + ni * 16 + l15;
        const float bc = bias[col];
        const float Gqq = gqq[col], Bqq = bqq[col];
        const float Gqk = gqk[col], Bqk = bqk[col];
        const float Glq = glq[col], Blq = blq[col];
        const float Glk = glk[col], Blk = blk[col];
        const int row = m0 + wm + mi * 16 + l16 * 4;
        ushort4v p;
#pragma unroll
        for (int r = 0; r < 4; ++r) {
          const float sv = silu_f(acc[mi][ni][r] + bc);
          const size_t ad = (size_t)(row + r) * N + col;
          Cn[ad] = f2bf(sv * Gqq + Bqq);
          Cn2[ad] = f2bf(sv * Gqk + Bqk);
          Cn3[ad] = f2bf(sv * Glq + Blq);
          p[r] = f2bf(sv * Glk + Blk);
        }
        *(ushort4v*)&trw[(ni * 16 + l15) * 72 + mi * 16 + l16 * 4] = p;
      }
    wave_transposed_store(Ct, ct_stride, trw, (m0 + wm) >> 8, (m0 + wm) & 255, wn,
                          lane);
  }
}

// ---------------- per-chunk kv[e][h] = sum_c vT[e][c]*lkT[h][c] ----------------
__global__ __launch_bounds__(256) void kv_kernel(const u16* __restrict__ vT,
                                                 const u16* __restrict__ lkT,
                                                 u16* __restrict__ kv) {
  const int chunk = blockIdx.y;
  const int et = blockIdx.x;  // e-block of 128
  const int w = threadIdx.x >> 6, lane = threadIdx.x & 63;
  const int l15 = lane & 15, l16 = lane >> 4;
  const size_t vb = (size_t)chunk * (2048 * 256) + (size_t)et * (128 * 256);
  const size_t lb = (size_t)chunk * (128 * 256);
  const int we = (w >> 1) * 64, wh = (w & 1) * 64;
  floatx4 acc[4][4];
#pragma unroll
  for (int i = 0; i < 4; ++i)
#pragma unroll
    for (int j = 0; j < 4; ++j) acc[i][j] = fzero();
  for (int kk = 0; kk < 8; ++kk) {
    short8 av[4], bv[4];
#pragma unroll
    for (int mi = 0; mi < 4; ++mi)
      av[mi] = *(const short8*)&vT[vb + (size_t)(we + mi * 16 + l15) * 256 + kk * 32 +
                                   l16 * 8];
#pragma unroll
    for (int ni = 0; ni < 4; ++ni)
      bv[ni] = *(const short8*)&lkT[lb + (size_t)(wh + ni * 16 + l15) * 256 + kk * 32 +
                                    l16 * 8];
#pragma unroll
    for (int mi = 0; mi < 4; ++mi)
#pragma unroll
      for (int ni = 0; ni < 4; ++ni) acc[mi][ni] = mfma16(av[mi], bv[ni], acc[mi][ni]);
  }
  u16* out = kv + (size_t)chunk * (2048 * 128);
#pragma unroll
  for (int mi = 0; mi < 4; ++mi)
#pragma unroll
    for (int ni = 0; ni < 4; ++ni) {
      const int h = wh + ni * 16 + l15;
      const int e = et * 128 + we + mi * 16 + l16 * 4;
#pragma unroll
      for (int r = 0; r < 4; ++r) out[(size_t)(e + r) * 128 + h] = f2bf(acc[mi][ni][r]);
    }
}

// ---------------- exclusive cumsum over chunks (in place, bf16) ----------------
__global__ __launch_bounds__(256) void cumsum_kernel(u16* __restrict__ kv) {
  const int idx = blockIdx.x * 256 + threadIdx.x;  // 0..262143 (= 2048*128)
  const int b = blockIdx.y;
  float s = 0.f;
  for (int g = 0; g < 16; ++g) {
    const size_t a = (size_t)(b * 16 + g) * 262144 + idx;
    const float v = bf2f(kv[a]);
    kv[a] = f2bf(s);
    s += v;
  }
}

// ---------------- fused chunk attention ----------------
__global__ __launch_bounds__(256) void attn_kernel(
    const u16* __restrict__ qq, const u16* __restrict__ qk, const u16* __restrict__ lq,
    const u16* __restrict__ vT, const u16* __restrict__ kvT,
    u16* __restrict__ gate_op) {
  __shared__ u16 S[64][264];
  const int chunk = blockIdx.y;
  const int e0 = blockIdx.x * 256;
  const int tok0 = chunk * 256;
  const int w = threadIdx.x >> 6, lane = threadIdx.x & 63;
  const int l15 = lane & 15, l16 = lane >> 4;
  const float isc = 0.022097086912079608f;  // 1/sqrt(2048)
  const size_t vbase = (size_t)chunk * (2048 * 256);
  const size_t kbase = (size_t)chunk * (2048 * 128);
  const int ew = e0 + w * 64;

  for (int ns = 0; ns < 4; ++ns) {
    // ---- phase 1: S rows [ns*64+w*16, +16) = relu^2(mask(qq*qk^T/scale))
    const int r0 = ns * 64 + w * 16;
    short8 af[4];
#pragma unroll
    for (int kk = 0; kk < 4; ++kk)
      af[kk] = *(const short8*)&qq[(size_t)(tok0 + r0 + l15) * 128 + kk * 32 + l16 * 8];
    const int mt_cnt = (r0 >> 4) + 1;   // tiles with any unmasked entry
    const int mt_all = (ns + 1) * 4;    // tiles phase 2 will read
    const int srow = w * 16 + l16 * 4;
    for (int mt = 0; mt < mt_all; ++mt) {
      if (mt < mt_cnt) {
        floatx4 a = fzero();
#pragma unroll
        for (int kk = 0; kk < 4; ++kk) {
          short8 bq =
              *(const short8*)&qk[(size_t)(tok0 + mt * 16 + l15) * 128 + kk * 32 +
                                  l16 * 8];
          a = mfma16(af[kk], bq, a);
        }
        const int mcol = mt * 16 + l15;
#pragma unroll
        for (int r = 0; r < 4; ++r) {
          const int nrow = r0 + l16 * 4 + r;
          float sv = a[r] * isc;
          sv = (mcol <= nrow) ? sv : 0.f;
          sv = fmaxf(sv, 0.f);
          S[srow + r][mcol] = f2bf(sv * sv);
        }
      } else {
#pragma unroll
        for (int r = 0; r < 4; ++r) S[srow + r][mt * 16 + l15] = (u16)0;
      }
    }
    __syncthreads();

    // ---- phase 2: (S@v + lin_q@kv) * gate, wave covers e cols [ew, ew+64)
    floatx4 acc[4][4];
#pragma unroll
    for (int i = 0; i < 4; ++i)
#pragma unroll
      for (int j = 0; j < 4; ++j) acc[i][j] = fzero();

    const int ks = (ns + 1) * 2;  // causal truncation of K range
    for (int kk = 0; kk < ks; ++kk) {
      short8 sa[4];
#pragma unroll
      for (int nt = 0; nt < 4; ++nt)
        sa[nt] = *(const short8*)&S[nt * 16 + l15][kk * 32 + l16 * 8];
#pragma unroll
      for (int ei = 0; ei < 4; ++ei) {
        short8 vb = *(const short8*)&vT[vbase + (size_t)(ew + ei * 16 + l15) * 256 +
                                        kk * 32 + l16 * 8];
#pragma unroll
        for (int nt = 0; nt < 4; ++nt) acc[nt][ei] = mfma16(sa[nt], vb, acc[nt][ei]);
      }
    }
#pragma unroll
    for (int kk = 0; kk < 4; ++kk) {
      short8 la[4];
#pragma unroll
      for (int nt = 0; nt < 4; ++nt)
        la[nt] = *(const short8*)&lq[(size_t)(tok0 + ns * 64 + nt * 16 + l15) * 128 +
                                     kk * 32 + l16 * 8];
#pragma unroll
      for (int ei = 0; ei < 4; ++ei) {
        short8 kb = *(const short8*)&kvT[kbase + (size_t)(ew + ei * 16 + l15) * 128 +
                                         kk * 32 + l16 * 8];
#pragma unroll
        for (int nt = 0; nt < 4; ++nt) acc[nt][ei] = mfma16(la[nt], kb, acc[nt][ei]);
      }
    }
#pragma unroll
    for (int nt = 0; nt < 4; ++nt)
#pragma unroll
      for (int ei = 0; ei < 4; ++ei) {
        const int e_g = ew + ei * 16 + l15;
        const int nb = tok0 + ns * 64 + nt * 16 + l16 * 4;
#pragma unroll
        for (int r = 0; r < 4; ++r) {
          const size_t ad = (size_t)(nb + r) * 2048 + e_g;
          const float gv = bf2f(gate_op[ad]);
          gate_op[ad] = f2bf(acc[nt][ei][r] * gv);
        }
      }
    __syncthreads();
  }
}

extern "C" void kernel_launch(void* const* d_in, const int* in_sizes, int n_in,
                              void* d_out, int out_size, void* d_ws, size_t ws_size,
                              hipStream_t stream) {
  (void)in_sizes; (void)n_in; (void)out_size; (void)ws_size;
  const float* x = (const float*)d_in[0];
  const float* Wv = (const float*)d_in[1];
  const float* bv = (const float*)d_in[2];
  const float* Wg = (const float*)d_in[3];
  const float* bg = (const float*)d_in[4];
  const float* Win = (const float*)d_in[5];
  const float* bin = (const float*)d_in[6];
  const float* Wout = (const float*)d_in[7];
  const float* bout = (const float*)d_in[8];
  const float* gqq = (const float*)d_in[9];
  const float* bqq = (const float*)d_in[10];
  const float* gqk = (const float*)d_in[11];
  const float* bqk = (const float*)d_in[12];
  const float* glq = (const float*)d_in[13];
  const float* blq = (const float*)d_in[14];
  const float* glk = (const float*)d_in[15];
  const float* blk = (const float*)d_in[16];

  char* p = (char*)d_ws;
  u16* xb = (u16*)p;   p += (size_t)16384 * 1024 * 2;
  u16* wvT = (u16*)p;  p += (size_t)2048 * 1024 * 2;   // [wvT; wgT] = merged Bt[4096][1024]
  u16* wgT = (u16*)p;  p += (size_t)2048 * 1024 * 2;
  u16* winT = (u16*)p; p += (size_t)128 * 1024 * 2;
  u16* woT = (u16*)p;  p += (size_t)1024 * 2048 * 2;
  u16* vTb = (u16*)p;  p += (size_t)64 * 2048 * 256 * 2;
  u16* gate = (u16*)p; p += (size_t)16384 * 2048 * 2;  // gate, then op (in place)
  u16* qqb = (u16*)p;  p += (size_t)16384 * 128 * 2;
  u16* qkb = (u16*)p;  p += (size_t)16384 * 128 * 2;
  u16* lqb = (u16*)p;  p += (size_t)16384 * 128 * 2;
  u16* lkTb = (u16*)p; p += (size_t)64 * 128 * 256 * 2;
  u16* kvb = (u16*)p;  p += (size_t)64 * 2048 * 128 * 2;

  cast_x_kernel<<<16384, 256, 0, stream>>>(x, xb, 4194304);
  transpose_cast_kernel<<<dim3(64, 32), 256, 0, stream>>>(Wv, wvT, 1024, 2048);
  transpose_cast_kernel<<<dim3(64, 32), 256, 0, stream>>>(Wg, wgT, 1024, 2048);
  transpose_cast_kernel<<<dim3(4, 32), 256, 0, stream>>>(Win, winT, 1024, 128);
  transpose_cast_kernel<<<dim3(32, 64), 256, 0, stream>>>(Wout, woT, 2048, 1024);

  // merged v+gate GEMM: M=16384, N=4096 ([v | gate]), K=1024, 256^2 tiles
  gemm8<0><<<1024, 512, 0, stream>>>(xb, wvT, bv, bg, vTb, gate, nullptr);

  gemm_bt<2><<<128, 256, 0, stream>>>(
      xb, winT, 16384, 128, 1024, 0, bin, qqb, nullptr, lkTb, 128L * 256, qkb, lqb,
      gqq, bqq, gqk, bqk, glq, blq, glk, blk);

  kv_kernel<<<dim3(16, 64), 256, 0, stream>>>(vTb, lkTb, kvb);
  cumsum_kernel<<<dim3(1024, 4), 256, 0, stream>>>(kvb);
  attn_kernel<<<dim3(8, 64), 256, 0, stream>>>(qqb, qkb, lqb, vTb, kvb, gate);

  // final GEMM: M=16384, N=1024, K=2048, 256^2 tiles, fp32 + bias
  gemm8<1><<<256, 512, 0, stream>>>(gate, woT, bout, nullptr, nullptr, nullptr,
                                    (float*)d_out);
}